// Round 1
// baseline (21.299 us; speedup 1.0000x reference)
//
#include <hip/hip_runtime.h>

// MipNeRF: coarse cast_rays + resample_along_rays (inverse-CDF) + fine cast_rays.
// One block per ray, 128 threads. All global writes coalesced via LDS staging.

constexpr int B_RAYS = 8192;
constexpr int S      = 128;   // NUM_SAMPLES (intervals per cast)
constexpr int SP1    = 129;   // t-values per ray
constexpr float F32_EPS = 1.1920928955078125e-07f;

// flat output offsets, in return order:
// (t_coarse, means_c, covs_c, t_fine, means_f, covs_f)
constexpr long long O_TC = 0;
constexpr long long O_MC = O_TC + (long long)B_RAYS * SP1;
constexpr long long O_CC = O_MC + (long long)B_RAYS * S * 3;
constexpr long long O_TF = O_CC + (long long)B_RAYS * S * 3;
constexpr long long O_MF = O_TF + (long long)B_RAYS * SP1;
constexpr long long O_CF = O_MF + (long long)B_RAYS * S * 3;

// conical_frustum_to_gaussian (stable branch) + lift_gaussian for interval tid,
// staged into LDS then written coalesced. Caller guarantees sh_stage is free
// on entry and sh_tv is valid (post-barrier).
__device__ __forceinline__ void cast_and_store(
    const float* __restrict__ sh_tv,   // [SP1] t values
    float* __restrict__ sh_stage,      // [768] staging: 384 means, 384 covs
    float dx, float dy, float dz,
    float ox, float oy, float oz,
    float rad2, float dmag2,
    float* __restrict__ out_means,     // + b*384
    float* __restrict__ out_covs,      // + b*384
    int tid)
{
    float t0 = sh_tv[tid], t1 = sh_tv[tid + 1];
    float mu  = 0.5f * (t0 + t1);
    float hw  = 0.5f * (t1 - t0);
    float mu2 = mu * mu, hw2 = hw * hw, hw4 = hw2 * hw2;
    float den = 3.0f * mu2 + hw2;
    float t_mean = mu + (2.0f * mu * hw2) / den;
    float t_var  = hw2 * (1.0f / 3.0f)
                 - (4.0f / 15.0f) * ((hw4 * (12.0f * mu2 - hw2)) / (den * den));
    float r_var  = rad2 * (0.25f * mu2 + (5.0f / 12.0f) * hw2
                 - (4.0f / 15.0f) * (hw4 / den));

    float dxx = dx * dx, dyy = dy * dy, dzz = dz * dz;

    sh_stage[3 * tid + 0] = dx * t_mean + ox;
    sh_stage[3 * tid + 1] = dy * t_mean + oy;
    sh_stage[3 * tid + 2] = dz * t_mean + oz;
    sh_stage[384 + 3 * tid + 0] = t_var * dxx + r_var * (1.0f - dxx / dmag2);
    sh_stage[384 + 3 * tid + 1] = t_var * dyy + r_var * (1.0f - dyy / dmag2);
    sh_stage[384 + 3 * tid + 2] = t_var * dzz + r_var * (1.0f - dzz / dmag2);
    __syncthreads();
    #pragma unroll
    for (int j = 0; j < 3; ++j) {
        out_means[j * 128 + tid] = sh_stage[j * 128 + tid];
        out_covs [j * 128 + tid] = sh_stage[384 + j * 128 + tid];
    }
}

__global__ __launch_bounds__(128) void mipnerf_kernel(
    const float* __restrict__ origins,     // [B,3]
    const float* __restrict__ directions,  // [B,3]
    const float* __restrict__ radii,       // [B,1]
    const float* __restrict__ nearp,       // [B,1]
    const float* __restrict__ farp,        // [B,1]
    const float* __restrict__ weights,     // [B,S]
    float* __restrict__ out)
{
    const int b   = blockIdx.x;
    const int tid = threadIdx.x;

    __shared__ float sh_t[SP1];      // t_coarse (= bins)
    __shared__ float sh_tf[SP1];     // t_fine
    __shared__ float sh_cdf[SP1];
    __shared__ float sh_w[S];
    __shared__ float sh_stage[2 * S * 3];
    __shared__ float sh_red[2];
    __shared__ float sh_wavetot;

    const float ox = origins[3 * b], oy = origins[3 * b + 1], oz = origins[3 * b + 2];
    const float dx = directions[3 * b], dy = directions[3 * b + 1], dz = directions[3 * b + 2];
    const float rad  = radii[b];
    const float rad2 = rad * rad;
    const float nv = nearp[b], fv = farp[b];
    const float dmag2 = fmaxf(dx * dx + dy * dy + dz * dz, 1e-10f);

    // ---- t_coarse = near*(1-t) + far*t, t = i/128 ----
    for (int i = tid; i < SP1; i += 128) {
        float t  = (float)i * (1.0f / 128.0f);
        float tc = nv * (1.0f - t) + fv * t;
        sh_t[i] = tc;
        out[O_TC + (long long)b * SP1 + i] = tc;
    }
    // ---- stage weights (coalesced) ----
    sh_w[tid] = weights[(long long)b * S + tid];
    __syncthreads();

    // ---- coarse cast ----
    cast_and_store(sh_t, sh_stage, dx, dy, dz, ox, oy, oz, rad2, dmag2,
                   out + O_MC + (long long)b * S * 3,
                   out + O_CC + (long long)b * S * 3, tid);

    // ---- blur weights: wblur[i] = 0.5*(max(w[i-1],w[i]) + max(w[i],w[i+1])) + pad ----
    float wi  = sh_w[tid];
    float wml = fmaxf((tid > 0     ? sh_w[tid - 1] : wi), wi);
    float wmr = fmaxf(wi, (tid < S - 1 ? sh_w[tid + 1] : wi));
    float wb  = 0.5f * (wml + wmr) + 0.01f;

    // ---- block sum (2 waves) ----
    float v = wb;
    #pragma unroll
    for (int off = 32; off >= 1; off >>= 1) v += __shfl_down(v, off);
    if ((tid & 63) == 0) sh_red[tid >> 6] = v;
    __syncthreads();
    float wsum    = sh_red[0] + sh_red[1];
    float padding = fmaxf(1e-5f - wsum, 0.0f);
    float wstot   = wsum + padding;
    float pdf     = (wb + padding * (1.0f / (float)S)) / wstot;

    // ---- inclusive scan of pdf across 128 threads (shfl within wave, LDS across) ----
    float x   = pdf;
    int lane  = tid & 63;
    #pragma unroll
    for (int off = 1; off < 64; off <<= 1) {
        float y = __shfl_up(x, off);
        if (lane >= off) x += y;
    }
    if (tid == 63) sh_wavetot = x;
    __syncthreads();
    if (tid >= 64) x += sh_wavetot;

    // cdf = [0, min(cumsum(pdf[0..126]),1), 1]
    if (tid == 0) { sh_cdf[0] = 0.0f; sh_cdf[S] = 1.0f; }
    if (tid < S - 1) sh_cdf[tid + 1] = fminf(x, 1.0f);
    __syncthreads();

    // ---- inverse-CDF sample: u_s = s*(1-eps)/128, binary search largest k: cdf[k] <= u ----
    const float ustep = (1.0f - F32_EPS) * (1.0f / 128.0f);
    for (int s = tid; s < SP1; s += 128) {
        float u = (float)s * ustep;
        int lo = 0, hi = S;                 // invariant: cdf[lo] <= u < cdf[hi]
        #pragma unroll
        for (int it = 0; it < 7; ++it) {
            int mid = (lo + hi) >> 1;
            if (sh_cdf[mid] <= u) lo = mid; else hi = mid;
        }
        float cg0 = sh_cdf[lo], cg1 = sh_cdf[lo + 1];
        float bg0 = sh_t[lo],   bg1 = sh_t[lo + 1];
        float tt  = (u - cg0) / (cg1 - cg0);
        if (!(tt == tt)) tt = 0.0f;                  // nan_to_num(nan) -> 0
        tt = fminf(fmaxf(tt, 0.0f), 1.0f);           // clip (inf -> 1)
        float tf = bg0 + tt * (bg1 - bg0);
        sh_tf[s] = tf;
        out[O_TF + (long long)b * SP1 + s] = tf;
    }
    __syncthreads();

    // ---- fine cast ----
    cast_and_store(sh_tf, sh_stage, dx, dy, dz, ox, oy, oz, rad2, dmag2,
                   out + O_MF + (long long)b * S * 3,
                   out + O_CF + (long long)b * S * 3, tid);
}

extern "C" void kernel_launch(void* const* d_in, const int* in_sizes, int n_in,
                              void* d_out, int out_size, void* d_ws, size_t ws_size,
                              hipStream_t stream)
{
    const float* origins    = (const float*)d_in[0];
    const float* directions = (const float*)d_in[1];
    const float* radii      = (const float*)d_in[2];
    const float* nearp      = (const float*)d_in[3];
    const float* farp       = (const float*)d_in[4];
    const float* weights    = (const float*)d_in[5];
    float* out = (float*)d_out;

    mipnerf_kernel<<<B_RAYS, 128, 0, stream>>>(
        origins, directions, radii, nearp, farp, weights, out);
}

// Round 2
// 19.638 us; speedup vs baseline: 1.0846x; 1.0846x over previous
//
#include <hip/hip_runtime.h>

// MipNeRF coarse cast + blur/inverse-CDF resample + fine cast.
// One 64-lane WAVE per ray (no __syncthreads at all): cross-lane via shuffles
// + per-wave private LDS regions (wave-synchronous, in-order DS ops).
// 256-thread blocks = 4 independent waves = 4 rays; grid = 8192/4.

constexpr int B_RAYS = 8192;
constexpr int S      = 128;   // intervals per cast
constexpr int SP1    = 129;   // t values per ray
constexpr float F32_EPS = 1.1920928955078125e-07f;

// flat output offsets (return order: t_coarse, means_c, covs_c, t_fine, means_f, covs_f)
constexpr long long O_TC = 0;
constexpr long long O_MC = O_TC + (long long)B_RAYS * SP1;
constexpr long long O_CC = O_MC + (long long)B_RAYS * S * 3;
constexpr long long O_TF = O_CC + (long long)B_RAYS * S * 3;
constexpr long long O_MF = O_TF + (long long)B_RAYS * SP1;
constexpr long long O_CF = O_MF + (long long)B_RAYS * S * 3;

__device__ __forceinline__ void frustum(float t0, float t1, float rad2,
                                        float& tm, float& tv, float& rv)
{
    // conical_frustum_to_gaussian, stable branch
    float mu  = 0.5f * (t0 + t1);
    float hw  = 0.5f * (t1 - t0);
    float mu2 = mu * mu, hw2 = hw * hw, hw4 = hw2 * hw2;
    float den = 3.0f * mu2 + hw2;
    float rden = 1.0f / den;
    tm = mu + (2.0f * mu * hw2) * rden;
    tv = hw2 * (1.0f / 3.0f)
       - (4.0f / 15.0f) * (hw4 * (12.0f * mu2 - hw2)) * (rden * rden);
    rv = rad2 * (0.25f * mu2 + (5.0f / 12.0f) * hw2 - (4.0f / 15.0f) * hw4 * rden);
}

__device__ __forceinline__ float sel3(int c, float x, float y, float z)
{
    return (c == 0) ? x : ((c == 1) ? y : z);
}

__global__ __launch_bounds__(256) void mipnerf_kernel(
    const float* __restrict__ origins,     // [B,3]
    const float* __restrict__ directions,  // [B,3]
    const float* __restrict__ radii,       // [B,1]
    const float* __restrict__ nearp,       // [B,1]
    const float* __restrict__ farp,        // [B,1]
    const float* __restrict__ weights,     // [B,S]
    float* __restrict__ out)
{
    const int tid = threadIdx.x;
    const int w   = tid >> 6;   // wave id within block
    const int l   = tid & 63;   // lane
    const int b   = (blockIdx.x << 2) + w;   // ray id

    __shared__ float s_tm[4][128];
    __shared__ float s_tv[4][128];
    __shared__ float s_rv[4][128];
    __shared__ float s_cdf[4][132];
    __shared__ float s_tf[4][132];

    const float ox = origins[3*b+0], oy = origins[3*b+1], oz = origins[3*b+2];
    const float dx = directions[3*b+0], dy = directions[3*b+1], dz = directions[3*b+2];
    const float rad  = radii[b];
    const float rad2 = rad * rad;
    const float nv = nearp[b], fv = farp[b];
    const float dmag2 = fmaxf(dx*dx + dy*dy + dz*dz, 1e-10f);
    const float axx = dx*dx, ayy = dy*dy, azz = dz*dz;
    const float nxx = 1.0f - axx/dmag2, nyy = 1.0f - ayy/dmag2, nzz = 1.0f - azz/dmag2;

    // bins are affine in index -> no LDS needed for them
    auto bin = [&](int k) {
        float t = (float)k * (1.0f / 128.0f);
        return nv * (1.0f - t) + fv * t;
    };

    // coalesced float2 writer for means/covs of one cast
    auto write_cast = [&](float* __restrict__ om, float* __restrict__ oc) {
        #pragma unroll
        for (int j = 0; j < 3; ++j) {
            int f0 = 2 * (l + 64*j);           // even float index 0..382
            int ia = f0 / 3,      ca = f0 - 3*ia;
            int ib2 = (f0+1) / 3, cb = (f0+1) - 3*ib2;
            float tma = s_tm[w][ia], tmb = s_tm[w][ib2];
            float2 mv;
            mv.x = sel3(ca, dx, dy, dz) * tma + sel3(ca, ox, oy, oz);
            mv.y = sel3(cb, dx, dy, dz) * tmb + sel3(cb, ox, oy, oz);
            *reinterpret_cast<float2*>(om + f0) = mv;
            float2 cv;
            cv.x = s_tv[w][ia] * sel3(ca, axx, ayy, azz)
                 + s_rv[w][ia] * sel3(ca, nxx, nyy, nzz);
            cv.y = s_tv[w][ib2] * sel3(cb, axx, ayy, azz)
                 + s_rv[w][ib2] * sel3(cb, nxx, nyy, nzz);
            *reinterpret_cast<float2*>(oc + f0) = cv;
        }
    };

    // ---- t_coarse out (129 values) ----
    for (int s = l; s < SP1; s += 64)
        out[O_TC + (long long)b * SP1 + s] = bin(s);

    // ---- coarse frustum -> LDS ----
    #pragma unroll
    for (int j = 0; j < 2; ++j) {
        int i = l + 64*j;
        float tm, tv, rv;
        frustum(bin(i), bin(i+1), rad2, tm, tv, rv);
        s_tm[w][i] = tm; s_tv[w][i] = tv; s_rv[w][i] = rv;
    }
    __builtin_amdgcn_wave_barrier();

    // ---- write means_c / covs_c ----
    write_cast(out + O_MC + (long long)b * 384, out + O_CC + (long long)b * 384);
    __builtin_amdgcn_wave_barrier();

    // ---- weights (pair layout: lane holds w[2l], w[2l+1]) ----
    float2 wv = *reinterpret_cast<const float2*>(weights + (long long)b * S + 2*l);
    float wprev = __shfl_up(wv.y, 1);   if (l == 0)  wprev = wv.x;   // pad w[-1]=w[0]
    float wnext = __shfl_down(wv.x, 1); if (l == 63) wnext = wv.y;   // pad w[128]=w[127]
    float m0 = fmaxf(wprev, wv.x), m1 = fmaxf(wv.x, wv.y), m2 = fmaxf(wv.y, wnext);
    float wb0 = 0.5f * (m0 + m1) + 0.01f;
    float wb1 = 0.5f * (m1 + m2) + 0.01f;

    // ---- scan of pair sums (shfl inclusive scan over 64 lanes) ----
    float ps   = wb0 + wb1;
    float incl = ps;
    #pragma unroll
    for (int off = 1; off < 64; off <<= 1) {
        float y = __shfl_up(incl, off);
        if (l >= off) incl += y;
    }
    float total = __shfl(incl, 63);
    float pad   = fmaxf(1e-5f - total, 0.0f);
    float wstot = total + pad;
    float inv   = 1.0f / wstot;
    float padk  = pad * (1.0f / 128.0f);
    float excl  = incl - ps;

    // cdf[0]=0; cdf[k]=min(cumsum(pdf)[k-1],1) for k=1..127; cdf[128]=1
    float c1 = fminf((excl + wb0 + (float)(2*l + 1) * padk) * inv, 1.0f);
    float c2 = fminf((incl        + (float)(2*l + 2) * padk) * inv, 1.0f);
    s_cdf[w][2*l + 1] = c1;
    s_cdf[w][2*l + 2] = (l == 63) ? 1.0f : c2;
    if (l == 0) s_cdf[w][0] = 0.0f;
    __builtin_amdgcn_wave_barrier();

    // ---- inverse-CDF sampling: 129 samples, binary search LDS cdf ----
    const float ustep = (1.0f - F32_EPS) * (1.0f / 128.0f);
    for (int s = l; s < SP1; s += 64) {
        float u = (float)s * ustep;
        int lo = 0, hi = 128;             // invariant: cdf[lo] <= u < cdf[hi]
        #pragma unroll
        for (int it = 0; it < 7; ++it) {
            int mid = (lo + hi) >> 1;
            if (s_cdf[w][mid] <= u) lo = mid; else hi = mid;
        }
        float c0  = s_cdf[w][lo], cg1 = s_cdf[w][lo + 1];
        float tt  = (u - c0) / (cg1 - c0);
        if (!(tt == tt)) tt = 0.0f;                 // nan_to_num
        tt = fminf(fmaxf(tt, 0.0f), 1.0f);          // clip (inf -> 1)
        float b0  = bin(lo);
        float tf  = b0 + tt * (bin(lo + 1) - b0);
        s_tf[w][s] = tf;
        out[O_TF + (long long)b * SP1 + s] = tf;
    }
    __builtin_amdgcn_wave_barrier();

    // ---- fine frustum -> LDS (overwrite) ----
    #pragma unroll
    for (int j = 0; j < 2; ++j) {
        int i = l + 64*j;
        float tm, tv, rv;
        frustum(s_tf[w][i], s_tf[w][i+1], rad2, tm, tv, rv);
        s_tm[w][i] = tm; s_tv[w][i] = tv; s_rv[w][i] = rv;
    }
    __builtin_amdgcn_wave_barrier();

    // ---- write means_f / covs_f ----
    write_cast(out + O_MF + (long long)b * 384, out + O_CF + (long long)b * 384);
}

extern "C" void kernel_launch(void* const* d_in, const int* in_sizes, int n_in,
                              void* d_out, int out_size, void* d_ws, size_t ws_size,
                              hipStream_t stream)
{
    const float* origins    = (const float*)d_in[0];
    const float* directions = (const float*)d_in[1];
    const float* radii      = (const float*)d_in[2];
    const float* nearp      = (const float*)d_in[3];
    const float* farp       = (const float*)d_in[4];
    const float* weights    = (const float*)d_in[5];
    float* out = (float*)d_out;

    mipnerf_kernel<<<B_RAYS / 4, 256, 0, stream>>>(
        origins, directions, radii, nearp, farp, weights, out);
}